// Round 1
// baseline (167.707 us; speedup 1.0000x reference)
//
#include <hip/hip_runtime.h>

#define NCLS 5
#define NSAMP 4194304
#define BLOCK 256
// each thread handles 4 samples -> 1,048,576 threads -> 4096 blocks
#define GRID (NSAMP / 4 / BLOCK)

__device__ __forceinline__ void accum_sample(float l0, float l1, float l2, float l3, float l4,
                                             int t, float sums[NCLS], float cnts[NCLS]) {
    float m = fmaxf(fmaxf(fmaxf(l0, l1), fmaxf(l2, l3)), l4);
    float s = __expf(l0 - m) + __expf(l1 - m) + __expf(l2 - m) +
              __expf(l3 - m) + __expf(l4 - m);
    // select target logit without dynamic register indexing (cndmask chain)
    float lt = (t == 0) ? l0 : (t == 1) ? l1 : (t == 2) ? l2 : (t == 3) ? l3 : l4;
    float ce = __logf(s) + m - lt;
#pragma unroll
    for (int k = 0; k < NCLS; ++k) {
        bool hit = (t == k);
        sums[k] += hit ? ce : 0.0f;
        cnts[k] += hit ? 1.0f : 0.0f;
    }
}

__global__ __launch_bounds__(BLOCK) void mfe_partial(const float* __restrict__ inputs,
                                                     const int* __restrict__ targets,
                                                     float* __restrict__ acc /* 10 floats */) {
    const int tid = blockIdx.x * BLOCK + threadIdx.x;
    const int base = tid * 4;  // first sample index for this thread (multiple of 4)

    // 4 samples * 5 logits = 20 floats = five float4 loads, 16B-aligned
    // (base*NCLS*4 bytes = 80*tid bytes). Fully coalesced.
    const float4* in4 = (const float4*)(inputs + (size_t)base * NCLS);
    float4 a = in4[0];
    float4 b = in4[1];
    float4 c = in4[2];
    float4 d = in4[3];
    float4 e = in4[4];
    int4 t4 = *(const int4*)(targets + base);

    float sums[NCLS] = {0.f, 0.f, 0.f, 0.f, 0.f};
    float cnts[NCLS] = {0.f, 0.f, 0.f, 0.f, 0.f};

    accum_sample(a.x, a.y, a.z, a.w, b.x, t4.x, sums, cnts);
    accum_sample(b.y, b.z, b.w, c.x, c.y, t4.y, sums, cnts);
    accum_sample(c.z, c.w, d.x, d.y, d.z, t4.z, sums, cnts);
    accum_sample(d.w, e.x, e.y, e.z, e.w, t4.w, sums, cnts);

    // wave-64 shuffle reduction of 10 values
#pragma unroll
    for (int k = 0; k < NCLS; ++k) {
#pragma unroll
        for (int off = 32; off > 0; off >>= 1) {
            sums[k] += __shfl_down(sums[k], off, 64);
            cnts[k] += __shfl_down(cnts[k], off, 64);
        }
    }

    __shared__ float ls[BLOCK / 64][2 * NCLS];
    const int lane = threadIdx.x & 63;
    const int wave = threadIdx.x >> 6;
    if (lane == 0) {
#pragma unroll
        for (int k = 0; k < NCLS; ++k) {
            ls[wave][k] = sums[k];
            ls[wave][NCLS + k] = cnts[k];
        }
    }
    __syncthreads();

    if (threadIdx.x < 2 * NCLS) {
        float v = 0.f;
#pragma unroll
        for (int w = 0; w < BLOCK / 64; ++w) v += ls[w][threadIdx.x];
        atomicAdd(acc + threadIdx.x, v);  // device-scope by default on CDNA
    }
}

__global__ void mfe_final(const float* __restrict__ acc, float* __restrict__ out) {
    if (threadIdx.x == 0 && blockIdx.x == 0) {
        float total = 0.f;
#pragma unroll
        for (int k = 0; k < NCLS; ++k) {
            float cnt = acc[NCLS + k];
            if (cnt > 0.f) total += acc[k] / cnt;
        }
        out[0] = total;
    }
}

extern "C" void kernel_launch(void* const* d_in, const int* in_sizes, int n_in,
                              void* d_out, int out_size, void* d_ws, size_t ws_size,
                              hipStream_t stream) {
    const float* inputs = (const float*)d_in[0];
    const int* targets = (const int*)d_in[1];
    float* out = (float*)d_out;
    float* acc = (float*)d_ws;  // 10 floats: sums[5], counts[5]

    // d_ws is re-poisoned to 0xAA before every call — zero the accumulators.
    hipMemsetAsync(acc, 0, 2 * NCLS * sizeof(float), stream);

    mfe_partial<<<GRID, BLOCK, 0, stream>>>(inputs, targets, acc);
    mfe_final<<<1, 64, 0, stream>>>(acc, out);
}

// Round 2
// 137.456 us; speedup vs baseline: 1.2201x; 1.2201x over previous
//
#include <hip/hip_runtime.h>

#define NCLS 5
#define NSAMP 4194304
#define BLOCK 256
#define GRID 1024
#define NTHREADS (GRID * BLOCK)                 // 262144
#define ITERS (NSAMP / (NTHREADS * 4))          // 4 (each iter: 4 samples/thread)
#define NVALS (2 * NCLS)                        // 5 sums + 5 counts

__device__ __forceinline__ void accum_sample(float l0, float l1, float l2, float l3, float l4,
                                             int t, float sums[NCLS], float cnts[NCLS]) {
    float m = fmaxf(fmaxf(fmaxf(l0, l1), fmaxf(l2, l3)), l4);
    float s = __expf(l0 - m) + __expf(l1 - m) + __expf(l2 - m) +
              __expf(l3 - m) + __expf(l4 - m);
    float lt = (t == 0) ? l0 : (t == 1) ? l1 : (t == 2) ? l2 : (t == 3) ? l3 : l4;
    float ce = __logf(s) + m - lt;
#pragma unroll
    for (int k = 0; k < NCLS; ++k) {
        bool hit = (t == k);
        sums[k] += hit ? ce : 0.0f;
        cnts[k] += hit ? 1.0f : 0.0f;
    }
}

// Block-level reduction of 10 values -> thread j (j<10) holds total in ret.
// Returns via pointer; only threads 0..9 have valid result.
__device__ __forceinline__ void block_reduce_10(float sums[NCLS], float cnts[NCLS],
                                                float* result10 /* valid for tid<10 */) {
#pragma unroll
    for (int k = 0; k < NCLS; ++k) {
#pragma unroll
        for (int off = 32; off > 0; off >>= 1) {
            sums[k] += __shfl_down(sums[k], off, 64);
            cnts[k] += __shfl_down(cnts[k], off, 64);
        }
    }
    __shared__ float ls[BLOCK / 64][NVALS];
    const int lane = threadIdx.x & 63;
    const int wave = threadIdx.x >> 6;
    if (lane == 0) {
#pragma unroll
        for (int k = 0; k < NCLS; ++k) {
            ls[wave][k] = sums[k];
            ls[wave][NCLS + k] = cnts[k];
        }
    }
    __syncthreads();
    if (threadIdx.x < NVALS) {
        float v = 0.f;
#pragma unroll
        for (int w = 0; w < BLOCK / 64; ++w) v += ls[w][threadIdx.x];
        *result10 = v;
    }
}

__global__ __launch_bounds__(BLOCK) void mfe_partial(const float* __restrict__ inputs,
                                                     const int* __restrict__ targets,
                                                     float* __restrict__ partial /* [NVALS][GRID] */) {
    const int tid = blockIdx.x * BLOCK + threadIdx.x;

    float sums[NCLS] = {0.f, 0.f, 0.f, 0.f, 0.f};
    float cnts[NCLS] = {0.f, 0.f, 0.f, 0.f, 0.f};

#pragma unroll
    for (int it = 0; it < ITERS; ++it) {
        const int chunk = it * NTHREADS + tid;   // each chunk = 4 samples
        const int base = chunk * 4;
        const float4* in4 = (const float4*)(inputs + (size_t)base * NCLS);
        float4 a = in4[0];
        float4 b = in4[1];
        float4 c = in4[2];
        float4 d = in4[3];
        float4 e = in4[4];
        int4 t4 = *(const int4*)(targets + base);

        accum_sample(a.x, a.y, a.z, a.w, b.x, t4.x, sums, cnts);
        accum_sample(b.y, b.z, b.w, c.x, c.y, t4.y, sums, cnts);
        accum_sample(c.z, c.w, d.x, d.y, d.z, t4.z, sums, cnts);
        accum_sample(d.w, e.x, e.y, e.z, e.w, t4.w, sums, cnts);
    }

    float total;
    block_reduce_10(sums, cnts, &total);
    if (threadIdx.x < NVALS) {
        // SoA: partial[j * GRID + blockIdx.x]; plain stores, no atomics.
        partial[threadIdx.x * GRID + blockIdx.x] = total;
    }
}

__global__ __launch_bounds__(BLOCK) void mfe_final(const float* __restrict__ partial,
                                                   float* __restrict__ out) {
    // One block: each thread accumulates GRID/BLOCK entries per value j.
    float sums[NCLS];
    float cnts[NCLS];
#pragma unroll
    for (int k = 0; k < NCLS; ++k) {
        float s = 0.f, c = 0.f;
#pragma unroll
        for (int i = 0; i < GRID / BLOCK; ++i) {
            s += partial[k * GRID + threadIdx.x + i * BLOCK];
            c += partial[(NCLS + k) * GRID + threadIdx.x + i * BLOCK];
        }
        sums[k] = s;
        cnts[k] = c;
    }

    float total;
    block_reduce_10(sums, cnts, &total);

    __shared__ float fin[NVALS];
    if (threadIdx.x < NVALS) fin[threadIdx.x] = total;
    __syncthreads();
    if (threadIdx.x == 0) {
        float loss = 0.f;
#pragma unroll
        for (int k = 0; k < NCLS; ++k) {
            float cnt = fin[NCLS + k];
            if (cnt > 0.f) loss += fin[k] / cnt;
        }
        out[0] = loss;
    }
}

extern "C" void kernel_launch(void* const* d_in, const int* in_sizes, int n_in,
                              void* d_out, int out_size, void* d_ws, size_t ws_size,
                              hipStream_t stream) {
    const float* inputs = (const float*)d_in[0];
    const int* targets = (const int*)d_in[1];
    float* out = (float*)d_out;
    float* partial = (float*)d_ws;  // NVALS * GRID floats = 40 KB

    mfe_partial<<<GRID, BLOCK, 0, stream>>>(inputs, targets, partial);
    mfe_final<<<1, BLOCK, 0, stream>>>(partial, out);
}